// Round 9
// baseline (69.397 us; speedup 1.0000x reference)
//
#include <hip/hip_runtime.h>

// out[p][i][s][l] = log( sum_j sum_k exp(e1[p][(i+j)%2][s][k]) * exp(e2[p][j][k][l]) )
// Direct form (all-positive sums, bf16-safe; avoids Hadamard cancellation):
//   S0 = A0*B0 + A1*B1 ; S1 = A1*B0 + A0*B1 ; out_i = log(S_i)
// with Ai = exp(e1[i]) (64x64 [s][k]), Bj = exp(e2[j]) (64x64 [k][l]) per pair.
// Matmuls in bf16 MFMA (16x16x32, fp32 accum). exp<=~250 -> bf16-safe range.
//
// R9 (discriminating experiment): ONE block per pair (256 blocks x 512 thr).
// vs R8: per-CU HBM input share 96->64 KB (e2 no longer fetched+exp'd twice),
// still exactly one residency round (1 block/CU), LDS ~36 KB.

typedef short short4v __attribute__((ext_vector_type(4)));
typedef short short8v __attribute__((ext_vector_type(8)));
typedef float float4v __attribute__((ext_vector_type(4)));

#define LDA 72   // A row pitch (bf16): 144 B -> single ds_read_b128 frags
#define LDB 68   // B row pitch (bf16): 136 B -> ds_read_u16 gather ~2-way (free)

// exp then round-to-nearest-even bf16, as raw bits (measured-correct R7/R8)
__device__ __forceinline__ short expbf(float x) {
    float f = __expf(x);
    unsigned u = __builtin_bit_cast(unsigned, f);
    u += 0x7fffu + ((u >> 16) & 1u);
    return (short)(u >> 16);
}

__global__ __launch_bounds__(512) void trellis_mfma_kernel(
    const float* __restrict__ e1,
    const float* __restrict__ e2,
    float* __restrict__ out)
{
    __shared__ __align__(16) short A0s[64 * LDA];
    __shared__ __align__(16) short A1s[64 * LDA];
    __shared__ __align__(16) short B0s[64 * LDB];
    __shared__ __align__(16) short B1s[64 * LDB];

    const int tid = threadIdx.x;
    const size_t base = (size_t)blockIdx.x * 8192;   // one pair per block

    const float4* __restrict__ e1v = (const float4*)(e1 + base);
    const float4* __restrict__ e2v = (const float4*)(e2 + base);

    // ---- stage: exp -> bf16 into LDS, coalesced float4 global reads ----
    #pragma unroll
    for (int it = 0; it < 2; ++it) {          // A full: 1024 float4/matrix -> 2/thread
        const int f = it * 512 + tid;         // f = r*16 + c4, r in [0,64)
        const int r = f >> 4, c4 = f & 15;
        const float4 a0 = e1v[f];
        const float4 a1 = e1v[1024 + f];
        short4v p0, p1;
        p0.x = expbf(a0.x); p0.y = expbf(a0.y); p0.z = expbf(a0.z); p0.w = expbf(a0.w);
        p1.x = expbf(a1.x); p1.y = expbf(a1.y); p1.z = expbf(a1.z); p1.w = expbf(a1.w);
        *(short4v*)&A0s[r * LDA + c4 * 4] = p0;
        *(short4v*)&A1s[r * LDA + c4 * 4] = p1;
    }
    #pragma unroll
    for (int it = 0; it < 2; ++it) {          // B full: 1024 float4/matrix -> 2/thread
        const int f = it * 512 + tid;         // f = k*16 + c4
        const int k = f >> 4, c4 = f & 15;
        const float4 b0 = e2v[f];
        const float4 b1 = e2v[1024 + f];
        short4v p0, p1;
        p0.x = expbf(b0.x); p0.y = expbf(b0.y); p0.z = expbf(b0.z); p0.w = expbf(b0.w);
        p1.x = expbf(b1.x); p1.y = expbf(b1.y); p1.z = expbf(b1.z); p1.w = expbf(b1.w);
        *(short4v*)&B0s[k * LDB + c4 * 4] = p0;
        *(short4v*)&B1s[k * LDB + c4 * 4] = p1;
    }
    __syncthreads();

    // ---- MFMA: 8 waves, 16 output tiles (16x16). Wave w -> col tile ct=w&3,
    // row tiles rbase and rbase+32 where rbase = (w>>2)*16. ----
    const int w    = tid >> 6;
    const int lane = tid & 63;
    const int ln   = lane & 15;
    const int g    = lane >> 4;
    const int ct   = w & 3;
    const int rb   = (w >> 2) * 16;

    // A fragments: elem i = A[row][ks*32 + g*8 + i]  (single b128 each)
    short8v a0f[2][2], a1f[2][2];             // [t][ks], row tile t: rb + t*32
    #pragma unroll
    for (int t = 0; t < 2; ++t) {
        #pragma unroll
        for (int ks = 0; ks < 2; ++ks) {
            const int off = (rb + t * 32 + ln) * LDA + ks * 32 + g * 8;
            a0f[t][ks] = *(const short8v*)&A0s[off];
            a1f[t][ks] = *(const short8v*)&A1s[off];
        }
    }

    // B fragments: elem i = B[ks*32 + g*8 + i][ct*16 + ln]
    // (same slot->k bijection as A => contraction correct independent of HW k order)
    short8v b0f[2], b1f[2];
    #pragma unroll
    for (int ks = 0; ks < 2; ++ks) {
        const int kb  = ks * 32 + g * 8;
        const int col = ct * 16 + ln;
        short8v t0, t1;
        #pragma unroll
        for (int i = 0; i < 8; ++i) {
            t0[i] = B0s[(kb + i) * LDB + col];
            t1[i] = B1s[(kb + i) * LDB + col];
        }
        b0f[ks] = t0;
        b1f[ks] = t1;
    }

    float4v acc0[2] = {{0.f,0.f,0.f,0.f}, {0.f,0.f,0.f,0.f}};  // S0 = A0B0 + A1B1
    float4v acc1[2] = {{0.f,0.f,0.f,0.f}, {0.f,0.f,0.f,0.f}};  // S1 = A1B0 + A0B1
    #pragma unroll
    for (int t = 0; t < 2; ++t) {
        #pragma unroll
        for (int ks = 0; ks < 2; ++ks) {
            acc0[t] = __builtin_amdgcn_mfma_f32_16x16x32_bf16(a0f[t][ks], b0f[ks], acc0[t], 0, 0, 0);
            acc0[t] = __builtin_amdgcn_mfma_f32_16x16x32_bf16(a1f[t][ks], b1f[ks], acc0[t], 0, 0, 0);
            acc1[t] = __builtin_amdgcn_mfma_f32_16x16x32_bf16(a1f[t][ks], b0f[ks], acc1[t], 0, 0, 0);
            acc1[t] = __builtin_amdgcn_mfma_f32_16x16x32_bf16(a0f[t][ks], b1f[ks], acc1[t], 0, 0, 0);
        }
    }

    // ---- epilogue: log + store. D layout (m89-verified): col=ln, row=g*4+j ----
    #pragma unroll
    for (int t = 0; t < 2; ++t) {
        const int srow0 = rb + t * 32 + g * 4;
        const int col   = ct * 16 + ln;
        #pragma unroll
        for (int j = 0; j < 4; ++j) {
            const size_t o = base + (size_t)(srow0 + j) * 64 + col;
            out[o]        = __logf(acc0[t][j]);   // i = 0
            out[o + 4096] = __logf(acc1[t][j]);   // i = 1
        }
    }
}

extern "C" void kernel_launch(void* const* d_in, const int* in_sizes, int n_in,
                              void* d_out, int out_size, void* d_ws, size_t ws_size,
                              hipStream_t stream)
{
    const float* e1 = (const float*)d_in[0];
    const float* e2 = (const float*)d_in[1];
    float* out = (float*)d_out;
    // 256 pairs, one block each (one residency round: 1 block/CU)
    hipLaunchKernelGGL(trellis_mfma_kernel, dim3(256), dim3(512), 0, stream,
                       e1, e2, out);
}